// Round 5
// baseline (739.860 us; speedup 1.0000x reference)
//
#include <hip/hip_runtime.h>
#include <hip/hip_bf16.h>

typedef short s16x8 __attribute__((ext_vector_type(8)));
typedef short s16x4 __attribute__((ext_vector_type(4)));
typedef float f32x4 __attribute__((ext_vector_type(4)));
typedef unsigned short u16;

// B=512, G=131, M = B*G = 67072, all dims 512.
#define MROWS 67072
#define GSZ   131
// Vt layout: per batch, 512 rows (d) x 160 cols (k, padded), bf16. Lives in d_out.
#define VT_KSTRIDE 160
#define VT_BATCH   (512 * VT_KSTRIDE)

__device__ inline u16 f2bf(float f) {               // round-half-up bf16
    return (u16)((__float_as_uint(f) + 0x8000u) >> 16);
}
__device__ inline unsigned pack2(float a, float b) {
    unsigned ua = __float_as_uint(a) + 0x8000u;
    unsigned ub = __float_as_uint(b) + 0x8000u;
    return (ua >> 16) | (ub & 0xFFFF0000u);
}
__device__ inline f32x4 mfma16(s16x8 a, s16x8 b, f32x4 c) {
    return __builtin_amdgcn_mfma_f32_16x16x32_bf16(a, b, c, 0, 0, 0);
}
// async global->LDS, 16B per lane. LDS dest = wave-uniform base + lane*16.
typedef const __attribute__((address_space(1))) unsigned gas_u32;
typedef __attribute__((address_space(3))) unsigned las_u32;
__device__ inline void async16(const void* g, void* l) {
    __builtin_amdgcn_global_load_lds((gas_u32*)g, (las_u32*)l, 16, 0, 0);
}

// ---------------------------------------------------------------------------
// fp32 -> bf16 convert, 8 elems/thread, bandwidth-bound.
// ---------------------------------------------------------------------------
__global__ __launch_bounds__(256)
void cvt_kernel(const float* __restrict__ src, u16* __restrict__ dst, int n8) {
    int i = blockIdx.x * 256 + threadIdx.x;
    if (i >= n8) return;
    const float4* s4 = (const float4*)src;
    float4 a = s4[2 * (size_t)i], b = s4[2 * (size_t)i + 1];
    union { s16x8 v; unsigned u[4]; } o;
    o.u[0] = pack2(a.x, a.y); o.u[1] = pack2(a.z, a.w);
    o.u[2] = pack2(b.x, b.y); o.u[3] = pack2(b.z, b.w);
    *(s16x8*)(dst + 8 * (size_t)i) = o.v;
}

// ---------------------------------------------------------------------------
// All-bf16 NT GEMM: C[m,n] = sum_k A[m,k] * W[n,k]; M x 512 x 512.
// 128x128 tiles, BK=32, global_load_lds(16B) staging, XOR column swizzle.
// MODE 0: bf16 row-major out. MODE 1: transposed into Vt. MODE 2: fp32+bias.
// XCD swizzle: 4 n-tiles of an m-tile stay on one XCD (A rows L2-resident).
// ---------------------------------------------------------------------------
template<int MODE>
__global__ __launch_bounds__(256, 2)
void gemm_bt(const u16* __restrict__ A, const u16* __restrict__ Bw,
             void* __restrict__ Outp, const float* __restrict__ bias)
{
    extern __shared__ __align__(16) char smem[];
    u16* smA = (u16*)smem;             // 128 x 32, no pad (global_load_lds)
    u16* smB = (u16*)(smem + 8192);    // 128 x 32
    u16* smC = (u16*)smem;             // epilogue alias: 128 x 136

    const int tid  = threadIdx.x;
    const int lane = tid & 63;
    const int w    = tid >> 6;
    const int wm   = w >> 1, wn = w & 1;          // 2x2 waves of 64x64

    // XCD-aware id: grid 2096 = 8 * 262; same m-tile's 4 n-tiles share an XCD.
    const int id    = (int)(blockIdx.x & 7) * 262 + (int)(blockIdx.x >> 3);
    const int mbase = (id >> 2) * 128;
    const int nbase = (id & 3) * 128;

    // staging map: wave w, iter t in {0,1} -> LDS chunk (w*2+t)*1024B;
    // lane l -> row = w*32 + (l>>2) + 16t, col-group (global) = (l&3) ^ (row&3)
    const int srow = w * 32 + (lane >> 2);
    const int scg  = (lane & 3) ^ (srow & 3);
    const u16* agp = A  + (size_t)(mbase + srow) * 512 + scg * 8;
    const u16* bgp = Bw + (size_t)(nbase + srow) * 512 + scg * 8;
    u16* al = smA + w * 1024;
    u16* bl = smB + w * 1024;

    f32x4 acc[4][4];
#pragma unroll
    for (int i = 0; i < 4; ++i)
#pragma unroll
        for (int j = 0; j < 4; ++j) acc[i][j] = (f32x4){0.f, 0.f, 0.f, 0.f};

    const int lr = lane & 15;
    const int co = ((lane >> 4) ^ (lr & 3)) * 8;   // swizzled fragment col offset

    for (int kk = 0; kk < 16; ++kk) {
        const int k0 = kk * 32;
        async16(agp + k0,            al);
        async16(agp + k0 + 16 * 512, al + 512);
        async16(bgp + k0,            bl);
        async16(bgp + k0 + 16 * 512, bl + 512);
        __syncthreads();

        s16x8 afr[4], bfr[4];
#pragma unroll
        for (int mi = 0; mi < 4; ++mi)
            afr[mi] = *(const s16x8*)&smA[(wm * 64 + mi * 16 + lr) * 32 + co];
#pragma unroll
        for (int ni = 0; ni < 4; ++ni)
            bfr[ni] = *(const s16x8*)&smB[(wn * 64 + ni * 16 + lr) * 32 + co];
#pragma unroll
        for (int mi = 0; mi < 4; ++mi)
#pragma unroll
            for (int ni = 0; ni < 4; ++ni)
                acc[mi][ni] = mfma16(afr[mi], bfr[ni], acc[mi][ni]);
        __syncthreads();
    }

    // C/D layout: col = lane&15, row = (lane>>4)*4 + reg (m89-verified).
    if constexpr (MODE == 2) {
        float bv[4];
#pragma unroll
        for (int ni = 0; ni < 4; ++ni) bv[ni] = bias[nbase + wn * 64 + ni * 16 + lr];
        float* outp = (float*)Outp;
#pragma unroll
        for (int mi = 0; mi < 4; ++mi)
#pragma unroll
            for (int ni = 0; ni < 4; ++ni) {
                int row0 = wm * 64 + mi * 16 + (lane >> 4) * 4;
                int col  = nbase + wn * 64 + ni * 16 + lr;
#pragma unroll
                for (int r = 0; r < 4; ++r)
                    outp[(size_t)(mbase + row0 + r) * 512 + col] = acc[mi][ni][r] + bv[ni];
            }
    } else if constexpr (MODE == 0) {
#pragma unroll
        for (int mi = 0; mi < 4; ++mi)
#pragma unroll
            for (int ni = 0; ni < 4; ++ni) {
                int row0 = wm * 64 + mi * 16 + (lane >> 4) * 4;
                int col  = wn * 64 + ni * 16 + lr;
#pragma unroll
                for (int r = 0; r < 4; ++r)
                    smC[(row0 + r) * 136 + col] = f2bf(acc[mi][ni][r]);
            }
        __syncthreads();
        u16* outp = (u16*)Outp;
        int rr = tid >> 1, cs = (tid & 1) * 64;
#pragma unroll
        for (int j = 0; j < 8; ++j) {
            s16x8 v = *(const s16x8*)&smC[rr * 136 + cs + j * 8];
            *(s16x8*)(outp + (size_t)(mbase + rr) * 512 + nbase + cs + j * 8) = v;
        }
    } else { // MODE 1: transposed store into Vt[b][d][k]
#pragma unroll
        for (int mi = 0; mi < 4; ++mi)
#pragma unroll
            for (int ni = 0; ni < 4; ++ni) {
                int nl = wn * 64 + ni * 16 + lr;               // Ct row (d)
                int m0 = wm * 64 + mi * 16 + (lane >> 4) * 4;  // Ct col (m) base
                s16x4 pk;
#pragma unroll
                for (int r = 0; r < 4; ++r) pk[r] = (short)f2bf(acc[mi][ni][r]);
                *(s16x4*)&smC[nl * 136 + m0] = pk;
            }
        __syncthreads();
        u16* outp = (u16*)Outp;
        for (int i = 0; i < 32; ++i) {
            int n = w * 32 + i;
            int d = nbase + n;
#pragma unroll
            for (int hh = 0; hh < 2; ++hh) {
                int ml = hh * 64 + lane;
                unsigned mg = (unsigned)(mbase + ml);
                unsigned bb = mg / 131u;
                unsigned k2 = mg - bb * 131u;
                outp[(size_t)bb * VT_BATCH + (size_t)d * VT_KSTRIDE + k2] = smC[n * 136 + ml];
            }
        }
    }
}

// ---------------------------------------------------------------------------
// Attention: 1 WG = (batch b, 32-row q tile), XCD-swizzled so all 5 q-tiles
// of a batch share one XCD (K/Vt become L2 hits after first fetch).
// LDS: single 33280-B buffer. Qs (Q tile) lives through QK^T; the S scratch
// (32x148 f32) and P scratch (32x168 bf16) ALIAS it afterwards — their
// lifetimes are disjoint and separated by barriers. QK^T partials are held
// in VGPRs (statically indexed) until the Q reads are barrier-complete.
// 33280 B -> 4 WGs/CU (was 62976 B -> 2 WGs/CU, 21% occupancy, latency-bound).
// ---------------------------------------------------------------------------
__global__ __launch_bounds__(256, 4)
void attn_kernel(u16* __restrict__ QHb, const u16* __restrict__ Kb,
                 const u16* __restrict__ Vtb, const int* __restrict__ mask,
                 const int* __restrict__ evp)
{
    __shared__ __align__(16) u16 Qs[32 * 520];      // 33280 B, whole LDS budget
    float* Ss = (float*)Qs;                         // alias: 32 x 148 f32 (18944 B)
    u16*   Ps = Qs + 9472;                          // alias: 32 x 168 bf16 @ byte 18944

    const int tid  = threadIdx.x;
    const int lane = tid & 63;
    const int w    = tid >> 6;
    // grid 2560 = 8 * 320; 320 % 5 == 0, so a batch never straddles XCDs.
    const int id   = (int)(blockIdx.x & 7) * 320 + (int)(blockIdx.x >> 3);
    const int b    = id / 5;
    const int qt   = id - b * 5;
    const int q0   = qt * 32;
    const size_t rowbase = (size_t)b * GSZ;

    {
        int r = tid >> 3, cs = (tid & 7) * 64;
        int q = q0 + r;
        if (q < GSZ) {
            const u16* src = QHb + (rowbase + q) * 512 + cs;
#pragma unroll
            for (int j = 0; j < 8; ++j)
                *(s16x8*)&Qs[r * 520 + cs + j * 8] = *(const s16x8*)(src + j * 8);
        } else {
            s16x8 z = (s16x8){0,0,0,0,0,0,0,0};
#pragma unroll
            for (int j = 0; j < 8; ++j) *(s16x8*)&Qs[r * 520 + cs + j * 8] = z;
        }
    }
    __syncthreads();

    const int lr = lane & 15;
    const int lk = (lane >> 4) * 8;
    const float norm = 0.044194173824159216f; // 1/sqrt(512)

    // QK^T: up to 3 nt-tiles per wave (nt = w, w+4, w+8<9), partials in VGPRs.
    f32x4 sacc[3][2];
#pragma unroll
    for (int t = 0; t < 3; ++t) {
        sacc[t][0] = (f32x4){0.f,0.f,0.f,0.f};
        sacc[t][1] = (f32x4){0.f,0.f,0.f,0.f};
    }
#pragma unroll
    for (int t = 0; t < 3; ++t) {
        const int nt = w + 4 * t;
        if (nt < 9) {
            const u16* kbase = Kb + (rowbase + nt * 16 + lr) * 512 + lk;
#pragma unroll
            for (int ks = 0; ks < 16; ++ks) {
                s16x8 bfr = *(const s16x8*)(kbase + ks * 32);
                s16x8 a0  = *(const s16x8*)&Qs[(lr) * 520 + ks * 32 + lk];
                s16x8 a1  = *(const s16x8*)&Qs[(16 + lr) * 520 + ks * 32 + lk];
                sacc[t][0] = mfma16(a0, bfr, sacc[t][0]);
                sacc[t][1] = mfma16(a1, bfr, sacc[t][1]);
            }
        }
    }
    __syncthreads();          // all Qs reads complete -> safe to alias as Ss

#pragma unroll
    for (int t = 0; t < 3; ++t) {
        const int nt = w + 4 * t;
        if (nt < 9) {
            int col = nt * 16 + lr;
            int rb  = (lane >> 4) * 4;
#pragma unroll
            for (int r = 0; r < 4; ++r) {
                Ss[(rb + r) * 148 + col]      = sacc[t][0][r] * norm;
                Ss[(16 + rb + r) * 148 + col] = sacc[t][1][r] * norm;
            }
        }
    }
    __syncthreads();

    {
        int r = tid >> 3, sub = tid & 7;
        int q = q0 + r;
        bool midq = (q >= 80) && (q < 130);
        int ev = *evp;
        float fill = ev ? -__builtin_inff() : -30.0f;
        float sv[17];
        float mx = -__builtin_inff();
#pragma unroll
        for (int j = 0; j < 17; ++j) {
            int k = sub + 8 * j;
            float s = -__builtin_inff();
            if (k < GSZ) {
                bool mk = (mask[b * GSZ + k] > 0) || (midq && (k >= 80) && (k < 130));
                s = mk ? fill : Ss[r * 148 + k];
            }
            sv[j] = s;
            mx = fmaxf(mx, s);
        }
#pragma unroll
        for (int off = 1; off < 8; off <<= 1) mx = fmaxf(mx, __shfl_xor(mx, off, 64));
        float sum = 0.f;
#pragma unroll
        for (int j = 0; j < 17; ++j) {
            int k = sub + 8 * j;
            if (k < GSZ) sum += __expf(sv[j] - mx);
        }
#pragma unroll
        for (int off = 1; off < 8; off <<= 1) sum += __shfl_xor(sum, off, 64);
        float inv = 1.0f / sum;
#pragma unroll
        for (int j = 0; j < 17; ++j) {
            int k = sub + 8 * j;
            if (k < GSZ) {
                bool mk = (mask[b * GSZ + k] > 0) || (midq && (k >= 80) && (k < 130));
                float p = mk ? 0.0f : __expf(sv[j] - mx) * inv;
                Ps[r * 168 + k] = f2bf(p);
            }
        }
        for (int k = GSZ + sub; k < 160; k += 8) Ps[r * 168 + k] = 0;
    }
    __syncthreads();

    f32x4 hacc[2][8];
#pragma unroll
    for (int mi = 0; mi < 2; ++mi)
#pragma unroll
        for (int ni = 0; ni < 8; ++ni) hacc[mi][ni] = (f32x4){0.f,0.f,0.f,0.f};
    const u16* vtbase = Vtb + (size_t)b * VT_BATCH + (size_t)(w * 128 + lr) * VT_KSTRIDE + lk;
#pragma unroll
    for (int kc = 0; kc < 5; ++kc) {
        s16x8 a0 = *(const s16x8*)&Ps[(lr) * 168 + kc * 32 + lk];
        s16x8 a1 = *(const s16x8*)&Ps[(16 + lr) * 168 + kc * 32 + lk];
#pragma unroll
        for (int ni = 0; ni < 8; ++ni) {
            s16x8 bfr = *(const s16x8*)(vtbase + (size_t)ni * 16 * VT_KSTRIDE + kc * 32);
            hacc[0][ni] = mfma16(a0, bfr, hacc[0][ni]);
            hacc[1][ni] = mfma16(a1, bfr, hacc[1][ni]);
        }
    }
    __syncthreads();          // Ps reads complete -> safe to overwrite Qs

#pragma unroll
    for (int mi = 0; mi < 2; ++mi)
#pragma unroll
        for (int ni = 0; ni < 8; ++ni) {
            int row0 = mi * 16 + (lane >> 4) * 4;
            int col  = w * 128 + ni * 16 + lr;
#pragma unroll
            for (int r = 0; r < 4; ++r)
                Qs[(row0 + r) * 520 + col] = f2bf(hacc[mi][ni][r]);
        }
    __syncthreads();
    {
        int r = tid >> 3, cs = (tid & 7) * 64;
        int q = q0 + r;
        if (q < GSZ) {
            u16* dst = QHb + (rowbase + q) * 512 + cs;
#pragma unroll
            for (int j = 0; j < 8; ++j)
                *(s16x8*)(dst + j * 8) = *(const s16x8*)&Qs[r * 520 + cs + j * 8];
        }
    }
}

extern "C" void kernel_launch(void* const* d_in, const int* in_sizes, int n_in,
                              void* d_out, int out_size, void* d_ws, size_t ws_size,
                              hipStream_t stream) {
    const float* q    = (const float*)d_in[0];
    const int*   mask = (const int*)d_in[1];
    const int*   evp  = (const int*)d_in[3];
    const float* h    = (const float*)d_in[4];
    const float* Wq   = (const float*)d_in[5];
    const float* Wk   = (const float*)d_in[6];
    const float* Wv   = (const float*)d_in[7];
    const float* Wo   = (const float*)d_in[8];
    const float* bo   = (const float*)d_in[9];
    float* out = (float*)d_out;

    // ws layout (u16 elems): CVT(h/q) | Kbuf | Qbuf/heads | wWq wWk wWv wWo
    // Vt (83.9 MB) lives in d_out (137 MB) and is dead before final GEMM writes.
    u16* Cbuf = (u16*)d_ws;                            // 67072*512
    u16* Kbuf = Cbuf + (size_t)MROWS * 512;
    u16* Qbuf = Kbuf + (size_t)MROWS * 512;
    u16* wWq  = Qbuf + (size_t)MROWS * 512;
    u16* wWk  = wWq + 512 * 512;
    u16* wWv  = wWk + 512 * 512;
    u16* wWo  = wWv + 512 * 512;
    u16* Vtb  = (u16*)d_out;

    const int n8_big = MROWS * 512 / 8;   // 4,292,608
    const int n8_w   = 512 * 512 / 8;     // 32,768
    dim3 bb(256);
    dim3 gcvt((n8_big + 255) / 256), gcw((n8_w + 255) / 256);
    dim3 gg(2096);
    const size_t lds_big = 34816, lds_min = 16384;

    // convert weights
    cvt_kernel<<<gcw, bb, 0, stream>>>(Wq, wWq, n8_w);
    cvt_kernel<<<gcw, bb, 0, stream>>>(Wk, wWk, n8_w);
    cvt_kernel<<<gcw, bb, 0, stream>>>(Wv, wWv, n8_w);
    cvt_kernel<<<gcw, bb, 0, stream>>>(Wo, wWo, n8_w);

    // h -> bf16; K and V projections
    cvt_kernel<<<gcvt, bb, 0, stream>>>(h, Cbuf, n8_big);
    gemm_bt<0><<<gg, bb, lds_big, stream>>>(Cbuf, wWk, (void*)Kbuf, nullptr);
    gemm_bt<1><<<gg, bb, lds_big, stream>>>(Cbuf, wWv, (void*)Vtb, nullptr);

    // q -> bf16 (reuse Cbuf); Q projection
    cvt_kernel<<<gcvt, bb, 0, stream>>>(q, Cbuf, n8_big);
    gemm_bt<0><<<gg, bb, lds_big, stream>>>(Cbuf, wWq, (void*)Qbuf, nullptr);

    attn_kernel<<<dim3(2560), bb, 0, stream>>>(Qbuf, Kbuf, Vtb, mask, evp);

    gemm_bt<2><<<gg, bb, lds_min, stream>>>(Qbuf, wWo, (void*)out, bo);
}

// Round 12
// 731.552 us; speedup vs baseline: 1.0114x; 1.0114x over previous
//
#include <hip/hip_runtime.h>
#include <hip/hip_bf16.h>

typedef short s16x8 __attribute__((ext_vector_type(8)));
typedef short s16x4 __attribute__((ext_vector_type(4)));
typedef float f32x4 __attribute__((ext_vector_type(4)));
typedef unsigned short u16;

// B=512, G=131, M = B*G = 67072, all dims 512.
#define MROWS 67072
#define GSZ   131
// Vt layout: per batch, 512 rows (d) x 160 cols (k, padded), bf16. Lives in d_out.
#define VT_KSTRIDE 160
#define VT_BATCH   (512 * VT_KSTRIDE)

__device__ inline u16 f2bf(float f) {               // round-half-up bf16
    return (u16)((__float_as_uint(f) + 0x8000u) >> 16);
}
__device__ inline unsigned pack2(float a, float b) {
    unsigned ua = __float_as_uint(a) + 0x8000u;
    unsigned ub = __float_as_uint(b) + 0x8000u;
    return (ua >> 16) | (ub & 0xFFFF0000u);
}
__device__ inline f32x4 mfma16(s16x8 a, s16x8 b, f32x4 c) {
    return __builtin_amdgcn_mfma_f32_16x16x32_bf16(a, b, c, 0, 0, 0);
}
// async global->LDS, 16B per lane. LDS dest = wave-uniform base + lane*16.
typedef const __attribute__((address_space(1))) unsigned gas_u32;
typedef __attribute__((address_space(3))) unsigned las_u32;
__device__ inline void async16(const void* g, void* l) {
    __builtin_amdgcn_global_load_lds((gas_u32*)g, (las_u32*)l, 16, 0, 0);
}

// ---------------------------------------------------------------------------
// fp32 -> bf16 convert, 8 elems/thread, bandwidth-bound.
// ---------------------------------------------------------------------------
__global__ __launch_bounds__(256)
void cvt_kernel(const float* __restrict__ src, u16* __restrict__ dst, int n8) {
    int i = blockIdx.x * 256 + threadIdx.x;
    if (i >= n8) return;
    const float4* s4 = (const float4*)src;
    float4 a = s4[2 * (size_t)i], b = s4[2 * (size_t)i + 1];
    union { s16x8 v; unsigned u[4]; } o;
    o.u[0] = pack2(a.x, a.y); o.u[1] = pack2(a.z, a.w);
    o.u[2] = pack2(b.x, b.y); o.u[3] = pack2(b.z, b.w);
    *(s16x8*)(dst + 8 * (size_t)i) = o.v;
}

// ---------------------------------------------------------------------------
// All-bf16 NT GEMM: C[m,n] = sum_k A[m,k] * W[n,k]; M x 512 x 512.
// 128x128 tiles, BK=32, global_load_lds(16B) staging, XOR column swizzle.
// MODE 0: bf16 row-major out. MODE 1: transposed into Vt. MODE 2: fp32+bias.
// XCD swizzle: 4 n-tiles of an m-tile stay on one XCD (A rows L2-resident).
// ---------------------------------------------------------------------------
template<int MODE>
__global__ __launch_bounds__(256, 2)
void gemm_bt(const u16* __restrict__ A, const u16* __restrict__ Bw,
             void* __restrict__ Outp, const float* __restrict__ bias)
{
    extern __shared__ __align__(16) char smem[];
    u16* smA = (u16*)smem;             // 128 x 32, no pad (global_load_lds)
    u16* smB = (u16*)(smem + 8192);    // 128 x 32
    u16* smC = (u16*)smem;             // epilogue alias: 128 x 136

    const int tid  = threadIdx.x;
    const int lane = tid & 63;
    const int w    = tid >> 6;
    const int wm   = w >> 1, wn = w & 1;          // 2x2 waves of 64x64

    // XCD-aware id: grid 2096 = 8 * 262; same m-tile's 4 n-tiles share an XCD.
    const int id    = (int)(blockIdx.x & 7) * 262 + (int)(blockIdx.x >> 3);
    const int mbase = (id >> 2) * 128;
    const int nbase = (id & 3) * 128;

    // staging map: wave w, iter t in {0,1} -> LDS chunk (w*2+t)*1024B;
    // lane l -> row = w*32 + (l>>2) + 16t, col-group (global) = (l&3) ^ (row&3)
    const int srow = w * 32 + (lane >> 2);
    const int scg  = (lane & 3) ^ (srow & 3);
    const u16* agp = A  + (size_t)(mbase + srow) * 512 + scg * 8;
    const u16* bgp = Bw + (size_t)(nbase + srow) * 512 + scg * 8;
    u16* al = smA + w * 1024;
    u16* bl = smB + w * 1024;

    f32x4 acc[4][4];
#pragma unroll
    for (int i = 0; i < 4; ++i)
#pragma unroll
        for (int j = 0; j < 4; ++j) acc[i][j] = (f32x4){0.f, 0.f, 0.f, 0.f};

    const int lr = lane & 15;
    const int co = ((lane >> 4) ^ (lr & 3)) * 8;   // swizzled fragment col offset

    for (int kk = 0; kk < 16; ++kk) {
        const int k0 = kk * 32;
        async16(agp + k0,            al);
        async16(agp + k0 + 16 * 512, al + 512);
        async16(bgp + k0,            bl);
        async16(bgp + k0 + 16 * 512, bl + 512);
        __syncthreads();

        s16x8 afr[4], bfr[4];
#pragma unroll
        for (int mi = 0; mi < 4; ++mi)
            afr[mi] = *(const s16x8*)&smA[(wm * 64 + mi * 16 + lr) * 32 + co];
#pragma unroll
        for (int ni = 0; ni < 4; ++ni)
            bfr[ni] = *(const s16x8*)&smB[(wn * 64 + ni * 16 + lr) * 32 + co];
#pragma unroll
        for (int mi = 0; mi < 4; ++mi)
#pragma unroll
            for (int ni = 0; ni < 4; ++ni)
                acc[mi][ni] = mfma16(afr[mi], bfr[ni], acc[mi][ni]);
        __syncthreads();
    }

    // C/D layout: col = lane&15, row = (lane>>4)*4 + reg (m89-verified).
    if constexpr (MODE == 2) {
        float bv[4];
#pragma unroll
        for (int ni = 0; ni < 4; ++ni) bv[ni] = bias[nbase + wn * 64 + ni * 16 + lr];
        float* outp = (float*)Outp;
#pragma unroll
        for (int mi = 0; mi < 4; ++mi)
#pragma unroll
            for (int ni = 0; ni < 4; ++ni) {
                int row0 = wm * 64 + mi * 16 + (lane >> 4) * 4;
                int col  = nbase + wn * 64 + ni * 16 + lr;
#pragma unroll
                for (int r = 0; r < 4; ++r)
                    outp[(size_t)(mbase + row0 + r) * 512 + col] = acc[mi][ni][r] + bv[ni];
            }
    } else if constexpr (MODE == 0) {
#pragma unroll
        for (int mi = 0; mi < 4; ++mi)
#pragma unroll
            for (int ni = 0; ni < 4; ++ni) {
                int row0 = wm * 64 + mi * 16 + (lane >> 4) * 4;
                int col  = wn * 64 + ni * 16 + lr;
#pragma unroll
                for (int r = 0; r < 4; ++r)
                    smC[(row0 + r) * 136 + col] = f2bf(acc[mi][ni][r]);
            }
        __syncthreads();
        u16* outp = (u16*)Outp;
        int rr = tid >> 1, cs = (tid & 1) * 64;
#pragma unroll
        for (int j = 0; j < 8; ++j) {
            s16x8 v = *(const s16x8*)&smC[rr * 136 + cs + j * 8];
            *(s16x8*)(outp + (size_t)(mbase + rr) * 512 + nbase + cs + j * 8) = v;
        }
    } else { // MODE 1: transposed store into Vt[b][d][k]
#pragma unroll
        for (int mi = 0; mi < 4; ++mi)
#pragma unroll
            for (int ni = 0; ni < 4; ++ni) {
                int nl = wn * 64 + ni * 16 + lr;               // Ct row (d)
                int m0 = wm * 64 + mi * 16 + (lane >> 4) * 4;  // Ct col (m) base
                s16x4 pk;
#pragma unroll
                for (int r = 0; r < 4; ++r) pk[r] = (short)f2bf(acc[mi][ni][r]);
                *(s16x4*)&smC[nl * 136 + m0] = pk;
            }
        __syncthreads();
        u16* outp = (u16*)Outp;
        for (int i = 0; i < 32; ++i) {
            int n = w * 32 + i;
            int d = nbase + n;
#pragma unroll
            for (int hh = 0; hh < 2; ++hh) {
                int ml = hh * 64 + lane;
                unsigned mg = (unsigned)(mbase + ml);
                unsigned bb = mg / 131u;
                unsigned k2 = mg - bb * 131u;
                outp[(size_t)bb * VT_BATCH + (size_t)d * VT_KSTRIDE + k2] = smC[n * 136 + ml];
            }
        }
    }
}

// ---------------------------------------------------------------------------
// Attention: 1 WG = (batch b, 32-row q tile), XCD-swizzled so all 5 q-tiles
// of a batch share one XCD. LDS: single 33280-B buffer with S/P aliased in
// (disjoint lifetimes, barrier-fenced). Round-5 postmortem: occupancy 21->38%
// bought only 4% — latency-bound on SERIAL global loads feeding MFMAs (K,Vt
// loaded one dwordx4 at a time inside the dep chain; concurrent same-batch
// WGs all miss L2 together -> ~HBM latency each). This version widens
// memory-level parallelism: 8-wide explicit load batches (kf[8]/vf[8]),
// ping-pong Vt prefetch across kc, kc0-Vt prefetch issued before softmax,
// mask/evp prefetched at kernel start. launch_bounds(256,3) gives the
// allocator register headroom for in-flight loads (measured occupancy is
// already ~3 WGs/CU; LDS still permits 4).
// ---------------------------------------------------------------------------
__global__ __launch_bounds__(256, 3)
void attn_kernel(u16* __restrict__ QHb, const u16* __restrict__ Kb,
                 const u16* __restrict__ Vtb, const int* __restrict__ mask,
                 const int* __restrict__ evp)
{
    __shared__ __align__(16) u16 Qs[32 * 520];      // 33280 B, whole LDS budget
    float* Ss = (float*)Qs;                         // alias: 32 x 148 f32 (18944 B)
    u16*   Ps = Qs + 9472;                          // alias: 32 x 168 bf16 @ byte 18944

    const int tid  = threadIdx.x;
    const int lane = tid & 63;
    const int w    = tid >> 6;
    // grid 2560 = 8 * 320; 320 % 5 == 0, so a batch never straddles XCDs.
    const int id   = (int)(blockIdx.x & 7) * 320 + (int)(blockIdx.x >> 3);
    const int b    = id / 5;
    const int qt   = id - b * 5;
    const int q0   = qt * 32;
    const size_t rowbase = (size_t)b * GSZ;

    const int r8  = tid >> 3;          // softmax row
    const int sub = tid & 7;           // softmax k-lane

    // --- early independent prefetches: mask row + evaluate flag -----------
    int ev = *evp;
    int mkpre[17];
#pragma unroll
    for (int j = 0; j < 17; ++j) {
        int k = sub + 8 * j;
        mkpre[j] = (k < GSZ) ? mask[b * GSZ + k] : 1;
    }

    {
        int cs = (tid & 7) * 64;
        int q = q0 + r8;
        if (q < GSZ) {
            const u16* src = QHb + (rowbase + q) * 512 + cs;
#pragma unroll
            for (int j = 0; j < 8; ++j)
                *(s16x8*)&Qs[r8 * 520 + cs + j * 8] = *(const s16x8*)(src + j * 8);
        } else {
            s16x8 z = (s16x8){0,0,0,0,0,0,0,0};
#pragma unroll
            for (int j = 0; j < 8; ++j) *(s16x8*)&Qs[r8 * 520 + cs + j * 8] = z;
        }
    }
    __syncthreads();

    const int lr = lane & 15;
    const int lk = (lane >> 4) * 8;
    const float norm = 0.044194173824159216f; // 1/sqrt(512)
    const u16* vtbase = Vtb + (size_t)b * VT_BATCH + (size_t)(w * 128 + lr) * VT_KSTRIDE + lk;

    // QK^T: up to 3 nt-tiles per wave (nt = w, w+4, w+8<9), partials in VGPRs.
    // K fragments loaded in 8-wide batches so 8 global loads are in flight.
    f32x4 sacc[3][2];
#pragma unroll
    for (int t = 0; t < 3; ++t) {
        sacc[t][0] = (f32x4){0.f,0.f,0.f,0.f};
        sacc[t][1] = (f32x4){0.f,0.f,0.f,0.f};
    }
#pragma unroll
    for (int t = 0; t < 3; ++t) {
        const int nt = w + 4 * t;
        if (nt < 9) {
            const u16* kbase = Kb + (rowbase + nt * 16 + lr) * 512 + lk;
#pragma unroll
            for (int h = 0; h < 2; ++h) {
                s16x8 kf[8];
#pragma unroll
                for (int j = 0; j < 8; ++j)
                    kf[j] = *(const s16x8*)(kbase + (h * 8 + j) * 32);
#pragma unroll
                for (int j = 0; j < 8; ++j) {
                    const int ks = h * 8 + j;
                    s16x8 a0 = *(const s16x8*)&Qs[(lr) * 520 + ks * 32 + lk];
                    s16x8 a1 = *(const s16x8*)&Qs[(16 + lr) * 520 + ks * 32 + lk];
                    sacc[t][0] = mfma16(a0, kf[j], sacc[t][0]);
                    sacc[t][1] = mfma16(a1, kf[j], sacc[t][1]);
                }
            }
        }
    }

    // Issue PV's kc=0 Vt fragment loads NOW — independent of S/softmax; their
    // ~HBM latency hides under the S-write + softmax phases.
    s16x8 vf[8];
#pragma unroll
    for (int j = 0; j < 8; ++j)
        vf[j] = *(const s16x8*)(vtbase + (size_t)j * 16 * VT_KSTRIDE);

    __syncthreads();          // all Qs reads complete -> safe to alias as Ss

#pragma unroll
    for (int t = 0; t < 3; ++t) {
        const int nt = w + 4 * t;
        if (nt < 9) {
            int col = nt * 16 + lr;
            int rb  = (lane >> 4) * 4;
#pragma unroll
            for (int r = 0; r < 4; ++r) {
                Ss[(rb + r) * 148 + col]      = sacc[t][0][r] * norm;
                Ss[(16 + rb + r) * 148 + col] = sacc[t][1][r] * norm;
            }
        }
    }
    __syncthreads();

    {
        int q = q0 + r8;
        bool midq = (q >= 80) && (q < 130);
        float fill = ev ? -__builtin_inff() : -30.0f;
        float sv[17];
        float mx = -__builtin_inff();
#pragma unroll
        for (int j = 0; j < 17; ++j) {
            int k = sub + 8 * j;
            float s = -__builtin_inff();
            if (k < GSZ) {
                bool mk = (mkpre[j] > 0) || (midq && (k >= 80) && (k < 130));
                s = mk ? fill : Ss[r8 * 148 + k];
            }
            sv[j] = s;
            mx = fmaxf(mx, s);
        }
#pragma unroll
        for (int off = 1; off < 8; off <<= 1) mx = fmaxf(mx, __shfl_xor(mx, off, 64));
        float sum = 0.f;
#pragma unroll
        for (int j = 0; j < 17; ++j) {
            int k = sub + 8 * j;
            if (k < GSZ) sum += __expf(sv[j] - mx);
        }
#pragma unroll
        for (int off = 1; off < 8; off <<= 1) sum += __shfl_xor(sum, off, 64);
        float inv = 1.0f / sum;
#pragma unroll
        for (int j = 0; j < 17; ++j) {
            int k = sub + 8 * j;
            if (k < GSZ) {
                bool mk = (mkpre[j] > 0) || (midq && (k >= 80) && (k < 130));
                float p = mk ? 0.0f : __expf(sv[j] - mx) * inv;
                Ps[r8 * 168 + k] = f2bf(p);
            }
        }
        for (int k = GSZ + sub; k < 160; k += 8) Ps[r8 * 168 + k] = 0;
    }
    __syncthreads();

    // PV: kc ping-pong — while kc's 16 MFMAs run, kc+1's 8 loads are in flight.
    f32x4 hacc[2][8];
#pragma unroll
    for (int mi = 0; mi < 2; ++mi)
#pragma unroll
        for (int ni = 0; ni < 8; ++ni) hacc[mi][ni] = (f32x4){0.f,0.f,0.f,0.f};
#pragma unroll
    for (int kc = 0; kc < 5; ++kc) {
        s16x8 vn[8];
        if (kc < 4) {
#pragma unroll
            for (int j = 0; j < 8; ++j)
                vn[j] = *(const s16x8*)(vtbase + (size_t)j * 16 * VT_KSTRIDE + (kc + 1) * 32);
        }
        s16x8 a0 = *(const s16x8*)&Ps[(lr) * 168 + kc * 32 + lk];
        s16x8 a1 = *(const s16x8*)&Ps[(16 + lr) * 168 + kc * 32 + lk];
#pragma unroll
        for (int ni = 0; ni < 8; ++ni) {
            hacc[0][ni] = mfma16(a0, vf[ni], hacc[0][ni]);
            hacc[1][ni] = mfma16(a1, vf[ni], hacc[1][ni]);
        }
        if (kc < 4) {
#pragma unroll
            for (int j = 0; j < 8; ++j) vf[j] = vn[j];
        }
    }
    __syncthreads();          // Ps reads complete -> safe to overwrite Qs

#pragma unroll
    for (int mi = 0; mi < 2; ++mi)
#pragma unroll
        for (int ni = 0; ni < 8; ++ni) {
            int row0 = mi * 16 + (lane >> 4) * 4;
            int col  = w * 128 + ni * 16 + lr;
#pragma unroll
            for (int r = 0; r < 4; ++r)
                Qs[(row0 + r) * 520 + col] = f2bf(hacc[mi][ni][r]);
        }
    __syncthreads();
    {
        int cs = (tid & 7) * 64;
        int q = q0 + r8;
        if (q < GSZ) {
            u16* dst = QHb + (rowbase + q) * 512 + cs;
#pragma unroll
            for (int j = 0; j < 8; ++j)
                *(s16x8*)(dst + j * 8) = *(const s16x8*)&Qs[r8 * 520 + cs + j * 8];
        }
    }
}

extern "C" void kernel_launch(void* const* d_in, const int* in_sizes, int n_in,
                              void* d_out, int out_size, void* d_ws, size_t ws_size,
                              hipStream_t stream) {
    const float* q    = (const float*)d_in[0];
    const int*   mask = (const int*)d_in[1];
    const int*   evp  = (const int*)d_in[3];
    const float* h    = (const float*)d_in[4];
    const float* Wq   = (const float*)d_in[5];
    const float* Wk   = (const float*)d_in[6];
    const float* Wv   = (const float*)d_in[7];
    const float* Wo   = (const float*)d_in[8];
    const float* bo   = (const float*)d_in[9];
    float* out = (float*)d_out;

    // ws layout (u16 elems): CVT(h/q) | Kbuf | Qbuf/heads | wWq wWk wWv wWo
    // Vt (83.9 MB) lives in d_out (137 MB) and is dead before final GEMM writes.
    u16* Cbuf = (u16*)d_ws;                            // 67072*512
    u16* Kbuf = Cbuf + (size_t)MROWS * 512;
    u16* Qbuf = Kbuf + (size_t)MROWS * 512;
    u16* wWq  = Qbuf + (size_t)MROWS * 512;
    u16* wWk  = wWq + 512 * 512;
    u16* wWv  = wWk + 512 * 512;
    u16* wWo  = wWv + 512 * 512;
    u16* Vtb  = (u16*)d_out;

    const int n8_big = MROWS * 512 / 8;   // 4,292,608
    const int n8_w   = 512 * 512 / 8;     // 32,768
    dim3 bb(256);
    dim3 gcvt((n8_big + 255) / 256), gcw((n8_w + 255) / 256);
    dim3 gg(2096);
    const size_t lds_big = 34816, lds_min = 16384;

    // convert weights
    cvt_kernel<<<gcw, bb, 0, stream>>>(Wq, wWq, n8_w);
    cvt_kernel<<<gcw, bb, 0, stream>>>(Wk, wWk, n8_w);
    cvt_kernel<<<gcw, bb, 0, stream>>>(Wv, wWv, n8_w);
    cvt_kernel<<<gcw, bb, 0, stream>>>(Wo, wWo, n8_w);

    // h -> bf16; K and V projections
    cvt_kernel<<<gcvt, bb, 0, stream>>>(h, Cbuf, n8_big);
    gemm_bt<0><<<gg, bb, lds_big, stream>>>(Cbuf, wWk, (void*)Kbuf, nullptr);
    gemm_bt<1><<<gg, bb, lds_big, stream>>>(Cbuf, wWv, (void*)Vtb, nullptr);

    // q -> bf16 (reuse Cbuf); Q projection
    cvt_kernel<<<gcvt, bb, 0, stream>>>(q, Cbuf, n8_big);
    gemm_bt<0><<<gg, bb, lds_big, stream>>>(Cbuf, wWq, (void*)Qbuf, nullptr);

    attn_kernel<<<dim3(2560), bb, 0, stream>>>(Qbuf, Kbuf, Vtb, mask, evp);

    gemm_bt<2><<<gg, bb, lds_min, stream>>>(Qbuf, wWo, (void*)out, bo);
}

// Round 14
// 697.364 us; speedup vs baseline: 1.0609x; 1.0490x over previous
//
#include <hip/hip_runtime.h>
#include <hip/hip_bf16.h>

typedef short s16x8 __attribute__((ext_vector_type(8)));
typedef short s16x4 __attribute__((ext_vector_type(4)));
typedef float f32x4 __attribute__((ext_vector_type(4)));
typedef unsigned short u16;

// B=512, G=131, M = B*G = 67072, all dims 512.
#define MROWS 67072
#define GSZ   131
// Vt layout: per batch, 512 rows (d) x 160 cols (k, padded), bf16. Lives in d_out.
#define VT_KSTRIDE 160
#define VT_BATCH   (512 * VT_KSTRIDE)

__device__ inline u16 f2bf(float f) {               // round-half-up bf16
    return (u16)((__float_as_uint(f) + 0x8000u) >> 16);
}
__device__ inline unsigned pack2(float a, float b) {
    unsigned ua = __float_as_uint(a) + 0x8000u;
    unsigned ub = __float_as_uint(b) + 0x8000u;
    return (ua >> 16) | (ub & 0xFFFF0000u);
}
__device__ inline f32x4 mfma16(s16x8 a, s16x8 b, f32x4 c) {
    return __builtin_amdgcn_mfma_f32_16x16x32_bf16(a, b, c, 0, 0, 0);
}
// async global->LDS, 16B per lane. LDS dest = wave-uniform base + lane*16.
typedef const __attribute__((address_space(1))) unsigned gas_u32;
typedef __attribute__((address_space(3))) unsigned las_u32;
__device__ inline void async16(const void* g, void* l) {
    __builtin_amdgcn_global_load_lds((gas_u32*)g, (las_u32*)l, 16, 0, 0);
}

// ---------------------------------------------------------------------------
// fp32 -> bf16 convert, 8 elems/thread, bandwidth-bound.
// ---------------------------------------------------------------------------
__global__ __launch_bounds__(256)
void cvt_kernel(const float* __restrict__ src, u16* __restrict__ dst, int n8) {
    int i = blockIdx.x * 256 + threadIdx.x;
    if (i >= n8) return;
    const float4* s4 = (const float4*)src;
    float4 a = s4[2 * (size_t)i], b = s4[2 * (size_t)i + 1];
    union { s16x8 v; unsigned u[4]; } o;
    o.u[0] = pack2(a.x, a.y); o.u[1] = pack2(a.z, a.w);
    o.u[2] = pack2(b.x, b.y); o.u[3] = pack2(b.z, b.w);
    *(s16x8*)(dst + 8 * (size_t)i) = o.v;
}

// ---------------------------------------------------------------------------
// All-bf16 NT GEMM: C[m,n] = sum_k A[m,k] * W[n,k]; M x 512 x 512.
// 128x128 tiles, BK=64 (two 32-col slabs per barrier pair; K=512 -> 8 iters,
// halving the per-iteration vmcnt(0)+barrier drains that dominate at short K).
// global_load_lds(16B) staging, XOR column swizzle per 32-col slab.
// MODE 0: bf16 row-major out. MODE 1: transposed into Vt. MODE 2: fp32+bias.
// XCD swizzle: 4 n-tiles of an m-tile stay on one XCD (A rows L2-resident).
// ---------------------------------------------------------------------------
template<int MODE>
__global__ __launch_bounds__(256, 2)
void gemm_bt(const u16* __restrict__ A, const u16* __restrict__ Bw,
             void* __restrict__ Outp, const float* __restrict__ bias)
{
    extern __shared__ __align__(16) char smem[];
    u16* smA = (u16*)smem;             // 128 x 64 (two 128x32 slabs), 16 KB
    u16* smB = (u16*)(smem + 16384);   // 128 x 64, 16 KB
    u16* smC = (u16*)smem;             // epilogue alias: 128 x 136

    const int tid  = threadIdx.x;
    const int lane = tid & 63;
    const int w    = tid >> 6;
    const int wm   = w >> 1, wn = w & 1;          // 2x2 waves of 64x64

    // XCD-aware id: grid 2096 = 8 * 262; same m-tile's 4 n-tiles share an XCD.
    const int id    = (int)(blockIdx.x & 7) * 262 + (int)(blockIdx.x >> 3);
    const int mbase = (id >> 2) * 128;
    const int nbase = (id & 3) * 128;

    // staging map (per 32-col slab): wave w, t in {0,1} -> LDS chunk
    // (w*2+t)*1024B within the slab; lane l -> row = w*32 + (l>>2) + 16t,
    // col-group (global) = (l&3) ^ (row&3). Slab s adds +32 cols / +4096 u16.
    const int srow = w * 32 + (lane >> 2);
    const int scg  = (lane & 3) ^ (srow & 3);
    const u16* agp = A  + (size_t)(mbase + srow) * 512 + scg * 8;
    const u16* bgp = Bw + (size_t)(nbase + srow) * 512 + scg * 8;
    u16* al = smA + w * 1024;
    u16* bl = smB + w * 1024;

    f32x4 acc[4][4];
#pragma unroll
    for (int i = 0; i < 4; ++i)
#pragma unroll
        for (int j = 0; j < 4; ++j) acc[i][j] = (f32x4){0.f, 0.f, 0.f, 0.f};

    const int lr = lane & 15;
    const int co = ((lane >> 4) ^ (lr & 3)) * 8;   // swizzled fragment col offset

    for (int kk = 0; kk < 8; ++kk) {
        const int k0 = kk * 64;
        // slab 0 (cols k0..k0+31)
        async16(agp + k0,            al);
        async16(agp + k0 + 16 * 512, al + 512);
        async16(bgp + k0,            bl);
        async16(bgp + k0 + 16 * 512, bl + 512);
        // slab 1 (cols k0+32..k0+63)
        async16(agp + k0 + 32,            al + 4096);
        async16(agp + k0 + 32 + 16 * 512, al + 4096 + 512);
        async16(bgp + k0 + 32,            bl + 4096);
        async16(bgp + k0 + 32 + 16 * 512, bl + 4096 + 512);
        __syncthreads();

#pragma unroll
        for (int s = 0; s < 2; ++s) {
            s16x8 afr[4], bfr[4];
#pragma unroll
            for (int mi = 0; mi < 4; ++mi)
                afr[mi] = *(const s16x8*)&smA[s * 4096 + (wm * 64 + mi * 16 + lr) * 32 + co];
#pragma unroll
            for (int ni = 0; ni < 4; ++ni)
                bfr[ni] = *(const s16x8*)&smB[s * 4096 + (wn * 64 + ni * 16 + lr) * 32 + co];
#pragma unroll
            for (int mi = 0; mi < 4; ++mi)
#pragma unroll
                for (int ni = 0; ni < 4; ++ni)
                    acc[mi][ni] = mfma16(afr[mi], bfr[ni], acc[mi][ni]);
        }
        __syncthreads();
    }

    // C/D layout: col = lane&15, row = (lane>>4)*4 + reg (m89-verified).
    if constexpr (MODE == 2) {
        float bv[4];
#pragma unroll
        for (int ni = 0; ni < 4; ++ni) bv[ni] = bias[nbase + wn * 64 + ni * 16 + lr];
        float* outp = (float*)Outp;
#pragma unroll
        for (int mi = 0; mi < 4; ++mi)
#pragma unroll
            for (int ni = 0; ni < 4; ++ni) {
                int row0 = wm * 64 + mi * 16 + (lane >> 4) * 4;
                int col  = nbase + wn * 64 + ni * 16 + lr;
#pragma unroll
                for (int r = 0; r < 4; ++r)
                    outp[(size_t)(mbase + row0 + r) * 512 + col] = acc[mi][ni][r] + bv[ni];
            }
    } else if constexpr (MODE == 0) {
#pragma unroll
        for (int mi = 0; mi < 4; ++mi)
#pragma unroll
            for (int ni = 0; ni < 4; ++ni) {
                int row0 = wm * 64 + mi * 16 + (lane >> 4) * 4;
                int col  = wn * 64 + ni * 16 + lr;
#pragma unroll
                for (int r = 0; r < 4; ++r)
                    smC[(row0 + r) * 136 + col] = f2bf(acc[mi][ni][r]);
            }
        __syncthreads();
        u16* outp = (u16*)Outp;
        int rr = tid >> 1, cs = (tid & 1) * 64;
#pragma unroll
        for (int j = 0; j < 8; ++j) {
            s16x8 v = *(const s16x8*)&smC[rr * 136 + cs + j * 8];
            *(s16x8*)(outp + (size_t)(mbase + rr) * 512 + nbase + cs + j * 8) = v;
        }
    } else { // MODE 1: transposed store into Vt[b][d][k]
#pragma unroll
        for (int mi = 0; mi < 4; ++mi)
#pragma unroll
            for (int ni = 0; ni < 4; ++ni) {
                int nl = wn * 64 + ni * 16 + lr;               // Ct row (d)
                int m0 = wm * 64 + mi * 16 + (lane >> 4) * 4;  // Ct col (m) base
                s16x4 pk;
#pragma unroll
                for (int r = 0; r < 4; ++r) pk[r] = (short)f2bf(acc[mi][ni][r]);
                *(s16x4*)&smC[nl * 136 + m0] = pk;
            }
        __syncthreads();
        u16* outp = (u16*)Outp;
        for (int i = 0; i < 32; ++i) {
            int n = w * 32 + i;
            int d = nbase + n;
#pragma unroll
            for (int hh = 0; hh < 2; ++hh) {
                int ml = hh * 64 + lane;
                unsigned mg = (unsigned)(mbase + ml);
                unsigned bb = mg / 131u;
                unsigned k2 = mg - bb * 131u;
                outp[(size_t)bb * VT_BATCH + (size_t)d * VT_KSTRIDE + k2] = smC[n * 136 + ml];
            }
        }
    }
}

// ---------------------------------------------------------------------------
// Attention: 1 WG = (batch b, 32-row q tile), XCD-swizzled so all 5 q-tiles
// of a batch share one XCD. LDS: single 33280-B buffer with S/P aliased in
// (disjoint lifetimes, barrier-fenced). 8-wide load batches (kf[8]/vf[8]),
// ping-pong Vt prefetch across kc, kc0-Vt prefetch issued before softmax,
// mask/evp prefetched at kernel start. Measured (R12): 153 us, occ 29%,
// MfmaUtil 6.5 — two latency levers (occupancy, MLP) each bought ~5%;
// kernel kept as-is while the GEMM block (the larger e2e share) is attacked.
// ---------------------------------------------------------------------------
__global__ __launch_bounds__(256, 3)
void attn_kernel(u16* __restrict__ QHb, const u16* __restrict__ Kb,
                 const u16* __restrict__ Vtb, const int* __restrict__ mask,
                 const int* __restrict__ evp)
{
    __shared__ __align__(16) u16 Qs[32 * 520];      // 33280 B, whole LDS budget
    float* Ss = (float*)Qs;                         // alias: 32 x 148 f32 (18944 B)
    u16*   Ps = Qs + 9472;                          // alias: 32 x 168 bf16 @ byte 18944

    const int tid  = threadIdx.x;
    const int lane = tid & 63;
    const int w    = tid >> 6;
    // grid 2560 = 8 * 320; 320 % 5 == 0, so a batch never straddles XCDs.
    const int id   = (int)(blockIdx.x & 7) * 320 + (int)(blockIdx.x >> 3);
    const int b    = id / 5;
    const int qt   = id - b * 5;
    const int q0   = qt * 32;
    const size_t rowbase = (size_t)b * GSZ;

    const int r8  = tid >> 3;          // softmax row
    const int sub = tid & 7;           // softmax k-lane

    // --- early independent prefetches: mask row + evaluate flag -----------
    int ev = *evp;
    int mkpre[17];
#pragma unroll
    for (int j = 0; j < 17; ++j) {
        int k = sub + 8 * j;
        mkpre[j] = (k < GSZ) ? mask[b * GSZ + k] : 1;
    }

    {
        int cs = (tid & 7) * 64;
        int q = q0 + r8;
        if (q < GSZ) {
            const u16* src = QHb + (rowbase + q) * 512 + cs;
#pragma unroll
            for (int j = 0; j < 8; ++j)
                *(s16x8*)&Qs[r8 * 520 + cs + j * 8] = *(const s16x8*)(src + j * 8);
        } else {
            s16x8 z = (s16x8){0,0,0,0,0,0,0,0};
#pragma unroll
            for (int j = 0; j < 8; ++j) *(s16x8*)&Qs[r8 * 520 + cs + j * 8] = z;
        }
    }
    __syncthreads();

    const int lr = lane & 15;
    const int lk = (lane >> 4) * 8;
    const float norm = 0.044194173824159216f; // 1/sqrt(512)
    const u16* vtbase = Vtb + (size_t)b * VT_BATCH + (size_t)(w * 128 + lr) * VT_KSTRIDE + lk;

    // QK^T: up to 3 nt-tiles per wave (nt = w, w+4, w+8<9), partials in VGPRs.
    // K fragments loaded in 8-wide batches so 8 global loads are in flight.
    f32x4 sacc[3][2];
#pragma unroll
    for (int t = 0; t < 3; ++t) {
        sacc[t][0] = (f32x4){0.f,0.f,0.f,0.f};
        sacc[t][1] = (f32x4){0.f,0.f,0.f,0.f};
    }
#pragma unroll
    for (int t = 0; t < 3; ++t) {
        const int nt = w + 4 * t;
        if (nt < 9) {
            const u16* kbase = Kb + (rowbase + nt * 16 + lr) * 512 + lk;
#pragma unroll
            for (int h = 0; h < 2; ++h) {
                s16x8 kf[8];
#pragma unroll
                for (int j = 0; j < 8; ++j)
                    kf[j] = *(const s16x8*)(kbase + (h * 8 + j) * 32);
#pragma unroll
                for (int j = 0; j < 8; ++j) {
                    const int ks = h * 8 + j;
                    s16x8 a0 = *(const s16x8*)&Qs[(lr) * 520 + ks * 32 + lk];
                    s16x8 a1 = *(const s16x8*)&Qs[(16 + lr) * 520 + ks * 32 + lk];
                    sacc[t][0] = mfma16(a0, kf[j], sacc[t][0]);
                    sacc[t][1] = mfma16(a1, kf[j], sacc[t][1]);
                }
            }
        }
    }

    // Issue PV's kc=0 Vt fragment loads NOW — independent of S/softmax; their
    // ~HBM latency hides under the S-write + softmax phases.
    s16x8 vf[8];
#pragma unroll
    for (int j = 0; j < 8; ++j)
        vf[j] = *(const s16x8*)(vtbase + (size_t)j * 16 * VT_KSTRIDE);

    __syncthreads();          // all Qs reads complete -> safe to alias as Ss

#pragma unroll
    for (int t = 0; t < 3; ++t) {
        const int nt = w + 4 * t;
        if (nt < 9) {
            int col = nt * 16 + lr;
            int rb  = (lane >> 4) * 4;
#pragma unroll
            for (int r = 0; r < 4; ++r) {
                Ss[(rb + r) * 148 + col]      = sacc[t][0][r] * norm;
                Ss[(16 + rb + r) * 148 + col] = sacc[t][1][r] * norm;
            }
        }
    }
    __syncthreads();

    {
        int q = q0 + r8;
        bool midq = (q >= 80) && (q < 130);
        float fill = ev ? -__builtin_inff() : -30.0f;
        float sv[17];
        float mx = -__builtin_inff();
#pragma unroll
        for (int j = 0; j < 17; ++j) {
            int k = sub + 8 * j;
            float s = -__builtin_inff();
            if (k < GSZ) {
                bool mk = (mkpre[j] > 0) || (midq && (k >= 80) && (k < 130));
                s = mk ? fill : Ss[r8 * 148 + k];
            }
            sv[j] = s;
            mx = fmaxf(mx, s);
        }
#pragma unroll
        for (int off = 1; off < 8; off <<= 1) mx = fmaxf(mx, __shfl_xor(mx, off, 64));
        float sum = 0.f;
#pragma unroll
        for (int j = 0; j < 17; ++j) {
            int k = sub + 8 * j;
            if (k < GSZ) sum += __expf(sv[j] - mx);
        }
#pragma unroll
        for (int off = 1; off < 8; off <<= 1) sum += __shfl_xor(sum, off, 64);
        float inv = 1.0f / sum;
#pragma unroll
        for (int j = 0; j < 17; ++j) {
            int k = sub + 8 * j;
            if (k < GSZ) {
                bool mk = (mkpre[j] > 0) || (midq && (k >= 80) && (k < 130));
                float p = mk ? 0.0f : __expf(sv[j] - mx) * inv;
                Ps[r8 * 168 + k] = f2bf(p);
            }
        }
        for (int k = GSZ + sub; k < 160; k += 8) Ps[r8 * 168 + k] = 0;
    }
    __syncthreads();

    // PV: kc ping-pong — while kc's 16 MFMAs run, kc+1's 8 loads are in flight.
    f32x4 hacc[2][8];
#pragma unroll
    for (int mi = 0; mi < 2; ++mi)
#pragma unroll
        for (int ni = 0; ni < 8; ++ni) hacc[mi][ni] = (f32x4){0.f,0.f,0.f,0.f};
#pragma unroll
    for (int kc = 0; kc < 5; ++kc) {
        s16x8 vn[8];
        if (kc < 4) {
#pragma unroll
            for (int j = 0; j < 8; ++j)
                vn[j] = *(const s16x8*)(vtbase + (size_t)j * 16 * VT_KSTRIDE + (kc + 1) * 32);
        }
        s16x8 a0 = *(const s16x8*)&Ps[(lr) * 168 + kc * 32 + lk];
        s16x8 a1 = *(const s16x8*)&Ps[(16 + lr) * 168 + kc * 32 + lk];
#pragma unroll
        for (int ni = 0; ni < 8; ++ni) {
            hacc[0][ni] = mfma16(a0, vf[ni], hacc[0][ni]);
            hacc[1][ni] = mfma16(a1, vf[ni], hacc[1][ni]);
        }
        if (kc < 4) {
#pragma unroll
            for (int j = 0; j < 8; ++j) vf[j] = vn[j];
        }
    }
    __syncthreads();          // Ps reads complete -> safe to overwrite Qs

#pragma unroll
    for (int mi = 0; mi < 2; ++mi)
#pragma unroll
        for (int ni = 0; ni < 8; ++ni) {
            int row0 = mi * 16 + (lane >> 4) * 4;
            int col  = w * 128 + ni * 16 + lr;
#pragma unroll
            for (int r = 0; r < 4; ++r)
                Qs[(row0 + r) * 520 + col] = f2bf(hacc[mi][ni][r]);
        }
    __syncthreads();
    {
        int cs = (tid & 7) * 64;
        int q = q0 + r8;
        if (q < GSZ) {
            u16* dst = QHb + (rowbase + q) * 512 + cs;
#pragma unroll
            for (int j = 0; j < 8; ++j)
                *(s16x8*)(dst + j * 8) = *(const s16x8*)&Qs[r8 * 520 + cs + j * 8];
        }
    }
}

extern "C" void kernel_launch(void* const* d_in, const int* in_sizes, int n_in,
                              void* d_out, int out_size, void* d_ws, size_t ws_size,
                              hipStream_t stream) {
    const float* q    = (const float*)d_in[0];
    const int*   mask = (const int*)d_in[1];
    const int*   evp  = (const int*)d_in[3];
    const float* h    = (const float*)d_in[4];
    const float* Wq   = (const float*)d_in[5];
    const float* Wk   = (const float*)d_in[6];
    const float* Wv   = (const float*)d_in[7];
    const float* Wo   = (const float*)d_in[8];
    const float* bo   = (const float*)d_in[9];
    float* out = (float*)d_out;

    // ws layout (u16 elems): CVT(h/q) | Kbuf | Qbuf/heads | wWq wWk wWv wWo
    // Vt (83.9 MB) lives in d_out (137 MB) and is dead before final GEMM writes.
    u16* Cbuf = (u16*)d_ws;                            // 67072*512
    u16* Kbuf = Cbuf + (size_t)MROWS * 512;
    u16* Qbuf = Kbuf + (size_t)MROWS * 512;
    u16* wWq  = Qbuf + (size_t)MROWS * 512;
    u16* wWk  = wWq + 512 * 512;
    u16* wWv  = wWk + 512 * 512;
    u16* wWo  = wWv + 512 * 512;
    u16* Vtb  = (u16*)d_out;

    const int n8_big = MROWS * 512 / 8;   // 4,292,608
    const int n8_w   = 512 * 512 / 8;     // 32,768
    dim3 bb(256);
    dim3 gcvt((n8_big + 255) / 256), gcw((n8_w + 255) / 256);
    dim3 gg(2096);
    const size_t lds_big = 34816, lds_min = 32768;   // BK=64 staging = 32 KB

    // convert weights
    cvt_kernel<<<gcw, bb, 0, stream>>>(Wq, wWq, n8_w);
    cvt_kernel<<<gcw, bb, 0, stream>>>(Wk, wWk, n8_w);
    cvt_kernel<<<gcw, bb, 0, stream>>>(Wv, wWv, n8_w);
    cvt_kernel<<<gcw, bb, 0, stream>>>(Wo, wWo, n8_w);

    // h -> bf16; K and V projections
    cvt_kernel<<<gcvt, bb, 0, stream>>>(h, Cbuf, n8_big);
    gemm_bt<0><<<gg, bb, lds_big, stream>>>(Cbuf, wWk, (void*)Kbuf, nullptr);
    gemm_bt<1><<<gg, bb, lds_big, stream>>>(Cbuf, wWv, (void*)Vtb, nullptr);

    // q -> bf16 (reuse Cbuf); Q projection
    cvt_kernel<<<gcvt, bb, 0, stream>>>(q, Cbuf, n8_big);
    gemm_bt<0><<<gg, bb, lds_big, stream>>>(Cbuf, wWq, (void*)Qbuf, nullptr);

    attn_kernel<<<dim3(2560), bb, 0, stream>>>(Qbuf, Kbuf, Vtb, mask, evp);

    gemm_bt<2><<<gg, bb, lds_big, stream>>>(Qbuf, wWo, (void*)out, bo);
}